// Round 1
// baseline (719.782 us; speedup 1.0000x reference)
//
#include <hip/hip_runtime.h>

// Problem constants
#define B_   2
#define S_   2048
#define D_   2048
#define NQ_  32
#define NKV_ 8
#define HD_  64
// g = NQ/NKV = 4

typedef unsigned short u16;
typedef __bf16 bf16x8 __attribute__((ext_vector_type(8)));
typedef float  f32x4  __attribute__((ext_vector_type(4)));

__device__ inline u16 f2b(float f){
  union { float f; unsigned u; } v; v.f = f;
  unsigned r = (v.u + 0x7fffu + ((v.u >> 16) & 1u)) >> 16;
  return (u16)r;
}
__device__ inline float b2f(u16 b){
  union { unsigned u; float f; } v; v.u = ((unsigned)b) << 16;
  return v.f;
}

// ---------------- fp32 -> bf16 convert (vectorized, n4 = n/4) ----------------
__global__ void k_f2b(const float* __restrict__ src, u16* __restrict__ dst, int n4){
  int i = blockIdx.x * blockDim.x + threadIdx.x;
  if (i >= n4) return;
  float4 f = ((const float4*)src)[i];
  uint2 pk;
  pk.x = (unsigned)f2b(f.x) | ((unsigned)f2b(f.y) << 16);
  pk.y = (unsigned)f2b(f.z) | ((unsigned)f2b(f.w) << 16);
  ((uint2*)dst)[i] = pk;
}

// ---------------- GEMM: C[M,N] = A[M,K] * B[N,K]^T, bf16 in, fp32 acc --------
// 128x128 tile, BK=32, 4 waves (2x2), each wave 64x64 via 4x4 MFMA 16x16x32.
template<int WRITE_F32>
__global__ __launch_bounds__(256) void k_gemm_bt(const u16* __restrict__ A,
                                                 const u16* __restrict__ Bm,
                                                 void* __restrict__ C,
                                                 int N, int K){
  __shared__ __align__(16) u16 As[128*32];
  __shared__ __align__(16) u16 Bs[128*32];
  const int tid  = threadIdx.x;
  const int lane = tid & 63;
  const int wave = tid >> 6;
  const int wm = wave >> 1, wn = wave & 1;
  const int quad = lane >> 4, l16 = lane & 15;

  const u16* Ab = A  + (size_t)blockIdx.y * 128 * K;
  const u16* Bb = Bm + (size_t)blockIdx.x * 128 * K;

  f32x4 acc[4][4];
  for (int i = 0; i < 4; i++)
    for (int j = 0; j < 4; j++) acc[i][j] = (f32x4){0.f, 0.f, 0.f, 0.f};

  // staging: 512 chunks of 8 bf16 (16 B); thread t handles chunks t and t+256
  const int r0 = tid >> 2;             // row 0..63
  const int c0 = (tid & 3) * 8;        // col 0,8,16,24
  const int r1 = r0 + 64;

  for (int k0 = 0; k0 < K; k0 += 32){
    uint4 a0 = *(const uint4*)(Ab + (size_t)r0 * K + k0 + c0);
    uint4 a1 = *(const uint4*)(Ab + (size_t)r1 * K + k0 + c0);
    uint4 b0 = *(const uint4*)(Bb + (size_t)r0 * K + k0 + c0);
    uint4 b1 = *(const uint4*)(Bb + (size_t)r1 * K + k0 + c0);
    __syncthreads();
    *(uint4*)&As[r0*32 + c0] = a0;
    *(uint4*)&As[r1*32 + c0] = a1;
    *(uint4*)&Bs[r0*32 + c0] = b0;
    *(uint4*)&Bs[r1*32 + c0] = b1;
    __syncthreads();
    bf16x8 af[4], bfr[4];
    for (int i = 0; i < 4; i++)
      af[i]  = *(const bf16x8*)&As[(wm*64 + i*16 + l16)*32 + quad*8];
    for (int j = 0; j < 4; j++)
      bfr[j] = *(const bf16x8*)&Bs[(wn*64 + j*16 + l16)*32 + quad*8];
    for (int i = 0; i < 4; i++)
      for (int j = 0; j < 4; j++)
        acc[i][j] = __builtin_amdgcn_mfma_f32_16x16x32_bf16(af[i], bfr[j], acc[i][j], 0, 0, 0);
  }

  // epilogue: C/D layout col = lane&15, row = quad*4 + reg (m89/m91 verified)
  for (int i = 0; i < 4; i++){
    int row0 = blockIdx.y*128 + wm*64 + i*16 + quad*4;
    for (int j = 0; j < 4; j++){
      int col = blockIdx.x*128 + wn*64 + j*16 + l16;
      for (int r = 0; r < 4; r++){
        if (WRITE_F32) ((float*)C)[(size_t)(row0 + r) * N + col] = acc[i][j][r];
        else           ((u16*) C)[(size_t)(row0 + r) * N + col] = f2b(acc[i][j][r]);
      }
    }
  }
}

// ---------------- RoPE + repack q,k into (b,h,s,hd) ----------------
// qkv: (B*S, 3072) bf16 rows = [q 2048 | k 512 | v 512]
__global__ void k_rope(const u16* __restrict__ qkv, u16* __restrict__ qT, u16* __restrict__ kT){
  int i = blockIdx.x * blockDim.x + threadIdx.x;   // B*S*(NQ+NKV)*32 = 5,242,880
  int d2 = i & 31;
  int j  = i >> 5;
  int s  = j & (S_ - 1);
  int j2 = j >> 11;
  int hh = j2 % (NQ_ + NKV_);
  int b  = j2 / (NQ_ + NKV_);
  if (b >= B_) return;
  // inv_freq = 10000^(-d2/32) = exp(-d2 * ln(10000)/32)
  float invf = __expf(-(float)d2 * (9.210340371976184f / 32.0f));
  float ang  = (float)s * invf;
  float c = cosf(ang), sn = sinf(ang);
  const u16* srow = qkv + (size_t)(b*S_ + s) * 3072;
  if (hh < NQ_){
    int col = hh*64 + d2;
    float x1 = b2f(srow[col]), x2 = b2f(srow[col + 32]);
    u16* drow = qT + ((size_t)(b*NQ_ + hh) * S_ + s) * 64;
    drow[d2]      = f2b(x1*c - x2*sn);
    drow[d2 + 32] = f2b(x2*c + x1*sn);
  } else {
    int h = hh - NQ_;
    int col = 2048 + h*64 + d2;
    float x1 = b2f(srow[col]), x2 = b2f(srow[col + 32]);
    u16* drow = kT + ((size_t)(b*NKV_ + h) * S_ + s) * 64;
    drow[d2]      = f2b(x1*c - x2*sn);
    drow[d2 + 32] = f2b(x2*c + x1*sn);
  }
}

// ---------------- V transpose to (b,h,hd,s) ----------------
__global__ void k_vtrans(const u16* __restrict__ qkv, u16* __restrict__ vT){
  int i = blockIdx.x * blockDim.x + threadIdx.x;   // B*NKV*HD*S = 2,097,152
  int s  = i & (S_ - 1);
  int j  = i >> 11;
  int d  = j & 63;
  int j2 = j >> 6;
  int h  = j2 & 7;
  int b  = j2 >> 3;
  if (b >= B_) return;
  vT[i] = qkv[(size_t)(b*S_ + s) * 3072 + 2560 + h*64 + d];
}

// ---------------- flash attention (causal, GQA) ----------------
// grid: B*NQ*(S/64) blocks; 4 waves/block, each wave owns a 16-query tile.
// Q: (b,h,s,64) bf16; K: (b,kvh,s,64) bf16; V: (b,kvh,64,s) bf16.
__global__ __launch_bounds__(256) void k_attn(const u16* __restrict__ qT,
                                              const u16* __restrict__ kT,
                                              const u16* __restrict__ vT,
                                              u16* __restrict__ aout){
  __shared__ __align__(16) u16 P[4][16*40];   // per-wave 16x32 P tile, stride 40 (16B aligned rows)
  const int blk = blockIdx.x;
  const int qb  = blk & 31;          // q-block within sequence (S/64 = 32)
  const int bh  = blk >> 5;
  const int h   = bh & 31;
  const int b   = bh >> 5;
  const int kvh = h >> 2;            // repeat(k, 4): head h -> kv head h/4
  const int lane = threadIdx.x & 63, wave = threadIdx.x >> 6;
  const int quad = lane >> 4, l16 = lane & 15;
  const int qbase = qb*64 + wave*16;

  const u16* Qh = qT + (size_t)(b*NQ_ + h)   * S_ * 64;
  const u16* Kh = kT + (size_t)(b*NKV_ + kvh) * S_ * 64;
  const u16* Vh = vT + (size_t)(b*NKV_ + kvh) * 64 * S_;
  u16* Pw = P[wave];

  // Q A-fragments: A[m=l16][k=quad*8+j], two K-halves of HD=64
  bf16x8 qa0 = *(const bf16x8*)(Qh + (size_t)(qbase + l16)*64 + quad*8);
  bf16x8 qa1 = *(const bf16x8*)(Qh + (size_t)(qbase + l16)*64 + 32 + quad*8);

  f32x4 o[4];
  for (int n = 0; n < 4; n++) o[n] = (f32x4){0.f, 0.f, 0.f, 0.f};
  float mrow[4] = {-1e30f, -1e30f, -1e30f, -1e30f};
  float lrow[4] = {0.f, 0.f, 0.f, 0.f};

  const int kend = qb*64 + 64;       // uniform across the block -> barriers legal
  for (int k0 = 0; k0 < kend; k0 += 32){
    f32x4 sc[2];
    for (int t = 0; t < 2; t++){
      const u16* Kp = Kh + (size_t)(k0 + t*16 + l16)*64 + quad*8;
      bf16x8 kb0 = *(const bf16x8*)(Kp);
      bf16x8 kb1 = *(const bf16x8*)(Kp + 32);
      f32x4 z = (f32x4){0.f, 0.f, 0.f, 0.f};
      z = __builtin_amdgcn_mfma_f32_16x16x32_bf16(qa0, kb0, z, 0, 0, 0);
      z = __builtin_amdgcn_mfma_f32_16x16x32_bf16(qa1, kb1, z, 0, 0, 0);
      sc[t] = z;
    }
    for (int r = 0; r < 4; r++){
      const int qrow = qbase + quad*4 + r;
      float v0 = sc[0][r] * 0.125f;             // 1/sqrt(64)
      float v1 = sc[1][r] * 0.125f;
      if (k0 + l16 > qrow)      v0 = -1e30f;    // causal mask
      if (k0 + 16 + l16 > qrow) v1 = -1e30f;
      float rm = fmaxf(v0, v1);
      rm = fmaxf(rm, __shfl_xor(rm, 1, 64));
      rm = fmaxf(rm, __shfl_xor(rm, 2, 64));
      rm = fmaxf(rm, __shfl_xor(rm, 4, 64));
      rm = fmaxf(rm, __shfl_xor(rm, 8, 64));
      float mn = fmaxf(mrow[r], rm);
      float al = __expf(mrow[r] - mn);
      float p0 = __expf(v0 - mn);
      float p1 = __expf(v1 - mn);
      float rs = p0 + p1;
      rs += __shfl_xor(rs, 1, 64);
      rs += __shfl_xor(rs, 2, 64);
      rs += __shfl_xor(rs, 4, 64);
      rs += __shfl_xor(rs, 8, 64);
      lrow[r] = lrow[r]*al + rs;
      mrow[r] = mn;
      Pw[(quad*4 + r)*40 + l16]      = f2b(p0);
      Pw[(quad*4 + r)*40 + 16 + l16] = f2b(p1);
      for (int n = 0; n < 4; n++) o[n][r] *= al;
    }
    __syncthreads();
    // P as A-operand: A[m=l16][k=quad*8+j]
    bf16x8 pa = *(const bf16x8*)&Pw[l16*40 + quad*8];
    for (int n = 0; n < 4; n++){
      // V as B-operand: B[k=key][n=d], lane reads 8 consecutive keys (vT is d-major)
      bf16x8 vb = *(const bf16x8*)(Vh + (size_t)(n*16 + l16)*S_ + k0 + quad*8);
      o[n] = __builtin_amdgcn_mfma_f32_16x16x32_bf16(pa, vb, o[n], 0, 0, 0);
    }
    __syncthreads();
  }

  for (int r = 0; r < 4; r++){
    const int row = qbase + quad*4 + r;
    float inv = 1.0f / lrow[r];
    u16* drow = aout + (size_t)(b*S_ + row) * D_ + h*64;
    for (int n = 0; n < 4; n++) drow[n*16 + l16] = f2b(o[n][r] * inv);
  }
}

// ---------------- launcher ----------------
extern "C" void kernel_launch(void* const* d_in, const int* in_sizes, int n_in,
                              void* d_out, int out_size, void* d_ws, size_t ws_size,
                              hipStream_t stream){
  const float* x  = (const float*)d_in[0];
  // d_in[1] = attention_mask (all ones; reference never applies it) -> ignored
  const float* Wq = (const float*)d_in[2];
  const float* Wk = (const float*)d_in[3];
  const float* Wv = (const float*)d_in[4];
  const float* Wo = (const float*)d_in[5];

  char* ws = (char*)d_ws;
  u16* xb    = (u16*)(ws);               // 16 MB, x in bf16; later reused as attnOut
  u16* wqkvb = (u16*)(ws + 16777216);    // 12 MB, [Wq;Wk;Wv] bf16 (3072 x 2048)
  u16* wob   = (u16*)(ws + 29360128);    // 8 MB, Wo bf16
  u16* qkv   = (u16*)(ws + 37748736);    // 24 MB, QKV proj output bf16 (4096 x 3072)
  u16* qTp   = (u16*)(ws + 62914560);    // 16 MB, q (b,h,s,64) RoPE'd
  u16* kTp   = (u16*)(ws + 79691776);    // 4 MB,  k (b,kvh,s,64) RoPE'd
  u16* vTp   = (u16*)(ws + 83886080);    // 4 MB,  v (b,kvh,64,s)
  u16* attnOut = xb;                     // alias: xb dead after GEMM1

  // fp32 -> bf16
  k_f2b<<<dim3(8192), 256, 0, stream>>>(x,  xb, 2097152);
  k_f2b<<<dim3(4096), 256, 0, stream>>>(Wq, wqkvb,               1048576);
  k_f2b<<<dim3(1024), 256, 0, stream>>>(Wk, wqkvb + 2048*2048,   262144);
  k_f2b<<<dim3(1024), 256, 0, stream>>>(Wv, wqkvb + 2560*2048,   262144);
  k_f2b<<<dim3(4096), 256, 0, stream>>>(Wo, wob,                 1048576);

  // QKV projection: (4096 x 2048) * (3072 x 2048)^T -> bf16
  k_gemm_bt<0><<<dim3(3072/128, 4096/128), 256, 0, stream>>>(xb, wqkvb, qkv, 3072, 2048);

  // RoPE q,k + V transpose
  k_rope  <<<dim3(20480), 256, 0, stream>>>(qkv, qTp, kTp);
  k_vtrans<<<dim3(8192),  256, 0, stream>>>(qkv, vTp);

  // causal GQA flash attention
  k_attn<<<dim3(2048), 256, 0, stream>>>(qTp, kTp, vTp, attnOut);

  // output projection: (4096 x 2048) * (2048 x 2048)^T -> fp32 d_out
  k_gemm_bt<1><<<dim3(2048/128, 4096/128), 256, 0, stream>>>(attnOut, wob, d_out, 2048, 2048);
}